// Round 2
// baseline (561.550 us; speedup 1.0000x reference)
//
#include <hip/hip_runtime.h>

// ============================================================================
// AdapterAttention on gfx950: cast->bf16, 3 proj GEMMs (MFMA 16x16x32_bf16),
// fused RMSNorm+RoPE (scale baked into q'), V-transpose, flash attention
// (no-max-subtraction softmax, valid since |score|<=22.6), out-proj GEMM.
// R1 change: flash waves own 32 q-rows (2 A-subtiles) so K/V LDS fragments are
// reused 2x -> LDS-issue per FLOP halved (flash was LDS-pipe-bound: 17 b128
// per 16 MFMAs; model 104us vs measured 116us).
// ============================================================================

typedef __attribute__((ext_vector_type(8))) short bf16x8;
typedef __attribute__((ext_vector_type(4))) float f32x4;

#define AS1(p) ((__attribute__((address_space(1))) void*)(p))
#define AS3(p) ((__attribute__((address_space(3))) void*)(p))

__device__ __forceinline__ unsigned short f2bf(float f) {
  unsigned int u = __float_as_uint(f);
  u += 0x7fffu + ((u >> 16) & 1u);   // RNE; inputs are finite
  return (unsigned short)(u >> 16);
}

constexpr int B_ = 2, S_ = 2048, DM = 2048, H_ = 16, HD = 128;
constexpr int M_ = B_ * S_;  // 4096 rows

// ---------------- fp32 -> bf16 cast (vec4) ----------------
__global__ __launch_bounds__(256) void castbf(const float* __restrict__ X,
                                              unsigned short* __restrict__ Y, int n4) {
  int i = blockIdx.x * 256 + threadIdx.x;
  if (i >= n4) return;
  float4 v = ((const float4*)X)[i];
  ushort4 u;
  u.x = f2bf(v.x); u.y = f2bf(v.y); u.z = f2bf(v.z); u.w = f2bf(v.w);
  ((ushort4*)Y)[i] = u;
}

// ---------------- bf16 GEMM: C = A * W^T, 128x128 tile, BK=32 ----------------
__global__ __launch_bounds__(256) void gemm_bt(const unsigned short* __restrict__ A,
                                               const unsigned short* __restrict__ Bw,
                                               float* __restrict__ C,
                                               int M, int N, int K) {
  __shared__ unsigned short lA[128 * 32];
  __shared__ unsigned short lB[128 * 32];
  const int tid = threadIdx.x, wave = tid >> 6, lane = tid & 63;
  const int quad = lane >> 4, l16 = lane & 15;
  const int m0 = blockIdx.x * 128, n0 = blockIdx.y * 128;
  const int wm = (wave >> 1) * 64, wn = (wave & 1) * 64;
  f32x4 acc[4][4];
#pragma unroll
  for (int i = 0; i < 4; i++)
#pragma unroll
    for (int j = 0; j < 4; j++) acc[i][j] = (f32x4){0.f, 0.f, 0.f, 0.f};

  for (int k0 = 0; k0 < K; k0 += 32) {
    __syncthreads();  // prior-iter LDS reads done before restage
#pragma unroll
    for (int call = 0; call < 2; ++call) {
      int c = wave * 128 + call * 64 + lane;       // chunk id 0..511 (16B each)
      int row = c >> 2, s = c & 3;                 // tile row, stored slot
      int dc = s ^ ((row >> 1) & 3);               // swizzled source k-chunk
      __builtin_amdgcn_global_load_lds(AS1(A + (size_t)(m0 + row) * K + k0 + dc * 8),
                                       AS3(lA + (wave * 128 + call * 64) * 8), 16, 0, 0);
      __builtin_amdgcn_global_load_lds(AS1(Bw + (size_t)(n0 + row) * K + k0 + dc * 8),
                                       AS3(lB + (wave * 128 + call * 64) * 8), 16, 0, 0);
    }
    __syncthreads();  // staging complete (drains vmcnt)

    bf16x8 af[4], bfr[4];
#pragma unroll
    for (int i = 0; i < 4; i++) {
      int r = wm + i * 16 + l16;
      af[i] = *(const bf16x8*)(lA + r * 32 + (quad ^ ((r >> 1) & 3)) * 8);
      int cN = wn + i * 16 + l16;
      bfr[i] = *(const bf16x8*)(lB + cN * 32 + (quad ^ ((cN >> 1) & 3)) * 8);
    }
#pragma unroll
    for (int i = 0; i < 4; i++)
#pragma unroll
      for (int j = 0; j < 4; j++)
        acc[i][j] = __builtin_amdgcn_mfma_f32_16x16x32_bf16(af[i], bfr[j], acc[i][j], 0, 0, 0);
  }
  // C/D layout: row (A/M idx) = quad*4 + reg, col (B/N idx) = l16
#pragma unroll
  for (int i = 0; i < 4; i++)
#pragma unroll
    for (int j = 0; j < 4; j++) {
      float* cp = C + (size_t)(m0 + wm + i * 16 + quad * 4) * N + (n0 + wn + j * 16 + l16);
#pragma unroll
      for (int r = 0; r < 4; r++) cp[(size_t)r * N] = acc[i][j][r];
    }
}

// ---------------- fused RMSNorm + RoPE, (B,S,H,hd) f32 -> (B,H,S,hd) bf16 ----
__global__ __launch_bounds__(256) void normrope(const float* __restrict__ X,
                                                const float* __restrict__ Cs,
                                                const float* __restrict__ Sn,
                                                const float* __restrict__ W,
                                                unsigned short* __restrict__ Out,
                                                float scale) {
  int gw = (blockIdx.x * 256 + threadIdx.x) >> 6;  // (b*S+s)*H + h
  int lane = threadIdx.x & 63;
  int h = gw & 15, bs = gw >> 4;          // bs = b*S + s
  int s = bs & (S_ - 1), b = bs >> 11;    // S_ = 2048
  const float* xr = X + (size_t)gw * HD;
  float x0 = xr[lane], x1 = xr[lane + 64];
  float ss = x0 * x0 + x1 * x1;
#pragma unroll
  for (int off = 32; off > 0; off >>= 1) ss += __shfl_xor(ss, off);
  float rr = rsqrtf(ss * (1.0f / 128.0f) + 1e-6f);
  float n0 = x0 * rr * W[lane], n1 = x1 * rr * W[lane + 64];
  const float* cp = Cs + (size_t)bs * HD;
  const float* sp = Sn + (size_t)bs * HD;
  float o0 = (n0 * cp[lane] - n1 * sp[lane]) * scale;           // -second half * sin
  float o1 = (n1 * cp[lane + 64] + n0 * sp[lane + 64]) * scale; // +first half * sin
  unsigned short* orow = Out + (((size_t)(b * H_ + h)) * S_ + s) * HD;
  orow[lane] = f2bf(o0);
  orow[lane + 64] = f2bf(o1);
}

// ---------------- V: (B,S,H,hd) f32 -> (B*H, hd, Sk) bf16 (transposed) -------
__global__ __launch_bounds__(256) void vtrans(const float* __restrict__ Vf,
                                              unsigned short* __restrict__ Vt) {
  __shared__ unsigned short tile[128 * 72];  // [d][s], stride 72 (144B, 16B-aligned)
  const int tid = threadIdx.x;
  const int sc = blockIdx.x & 31;   // S_/64 chunks
  const int bh = blockIdx.x >> 5;
  const int b = bh >> 4, h = bh & 15;
  const int s0 = sc * 64;
#pragma unroll
  for (int it = 0; it < 8; ++it) {
    int ci = it * 256 + tid;                  // 2048 float4 chunks: 64 s x 32 dq
    int s = ci >> 5, dq = ci & 31;
    float4 v = *(const float4*)(Vf + ((size_t)(b * S_ + s0 + s)) * DM + h * HD + dq * 4);
    unsigned short* tp = tile + (dq * 4) * 72 + s;
    tp[0] = f2bf(v.x); tp[72] = f2bf(v.y); tp[144] = f2bf(v.z); tp[216] = f2bf(v.w);
  }
  __syncthreads();
#pragma unroll
  for (int it = 0; it < 4; ++it) {
    int cj = it * 256 + tid;                  // 1024 16B chunks: 128 d x 8 sc
    int d = cj >> 3, scx = cj & 7;
    bf16x8 vv = *(const bf16x8*)(tile + d * 72 + scx * 8);
    *(bf16x8*)(Vt + ((size_t)bh * HD + d) * S_ + s0 + scx * 8) = vv;
  }
}

// ---------------- flash attention (v2: 32 q-rows/wave, 128 q-rows/block) -----
// Q (BH,Sq,128) bf16 scale-baked; K (BH,Sk,128); V (BH,128,Sk); Y (B,Sq,2048) bf16
__global__ __launch_bounds__(256) void flash(const unsigned short* __restrict__ Q,
                                             const unsigned short* __restrict__ Kt,
                                             const unsigned short* __restrict__ Vt,
                                             unsigned short* __restrict__ Y) {
  __shared__ unsigned short lK[32 * HD];      // [key][dim], chunk-swizzled
  __shared__ unsigned short lV[HD * 32];      // [dim][key], chunk-swizzled
  __shared__ unsigned short lP[4 * 32 * 32];  // per-wave P scratch (2 subtiles)
  const int tid = threadIdx.x, wave = tid >> 6, lane = tid & 63;
  const int quad = lane >> 4, l16 = lane & 15;
  const int qb = blockIdx.x & 15;   // Sq/128
  const int bh = blockIdx.x >> 4;
  const int b = bh >> 4, h = bh & 15;
  const int q0 = qb * 128 + wave * 32;

  bf16x8 aq[2][4];
#pragma unroll
  for (int u = 0; u < 2; u++) {
    const unsigned short* qrow = Q + ((size_t)bh * S_ + q0 + u * 16 + l16) * HD;
#pragma unroll
    for (int t = 0; t < 4; t++) aq[u][t] = *(const bf16x8*)(qrow + t * 32 + quad * 8);
  }
  f32x4 o[2][8];
#pragma unroll
  for (int u = 0; u < 2; u++)
#pragma unroll
    for (int t = 0; t < 8; t++) o[u][t] = (f32x4){0.f, 0.f, 0.f, 0.f};
  float lsum[2][4] = {{0.f, 0.f, 0.f, 0.f}, {0.f, 0.f, 0.f, 0.f}};

  const unsigned short* kbase = Kt + (size_t)bh * S_ * HD;
  const unsigned short* vbase = Vt + (size_t)bh * HD * S_;
  unsigned short* lPw = lP + wave * 1024;
  const int mrow = quad * 4;
  const int xsl = (l16 >> 1) & 3;   // read-side swizzle for P and V frags

  for (int k0 = 0; k0 < S_; k0 += 32) {
    __syncthreads();
#pragma unroll
    for (int call = 0; call < 2; ++call) {
      int c = wave * 128 + call * 64 + lane;
      int key = c >> 4, sk = c & 15;
      int dck = sk ^ (key & 15);              // K swizzle: 16 chunks/row XOR key&15
      __builtin_amdgcn_global_load_lds(AS1(kbase + (size_t)(k0 + key) * HD + dck * 8),
                                       AS3(lK + (wave * 128 + call * 64) * 8), 16, 0, 0);
      int dv = c >> 2, sv = c & 3;
      int kc = sv ^ ((dv >> 1) & 3);          // V swizzle: 4 chunks/row XOR (d>>1)&3
      __builtin_amdgcn_global_load_lds(AS1(vbase + (size_t)dv * S_ + k0 + kc * 8),
                                       AS3(lV + (wave * 128 + call * 64) * 8), 16, 0, 0);
    }
    __syncthreads();

    // S = Q*K^T  (two 16-key column tiles x two 16-row q subtiles; K frags
    // read once, used by both subtiles)
    f32x4 s0[2] = {(f32x4){0.f, 0.f, 0.f, 0.f}, (f32x4){0.f, 0.f, 0.f, 0.f}};
    f32x4 s1[2] = {(f32x4){0.f, 0.f, 0.f, 0.f}, (f32x4){0.f, 0.f, 0.f, 0.f}};
    {
      const unsigned short* krow0 = lK + l16 * HD;          // keys 0..15
      const unsigned short* krow1 = lK + (16 + l16) * HD;   // keys 16..31
#pragma unroll
      for (int t = 0; t < 4; t++) {
        int dcq = t * 4 + quad;
        bf16x8 kf0 = *(const bf16x8*)(krow0 + (dcq ^ l16) * 8);
        bf16x8 kf1 = *(const bf16x8*)(krow1 + (dcq ^ l16) * 8);
#pragma unroll
        for (int u = 0; u < 2; u++) {
          s0[u] = __builtin_amdgcn_mfma_f32_16x16x32_bf16(aq[u][t], kf0, s0[u], 0, 0, 0);
          s1[u] = __builtin_amdgcn_mfma_f32_16x16x32_bf16(aq[u][t], kf1, s1[u], 0, 0, 0);
        }
      }
    }
    // softmax numerator (no max subtraction: |s| <= 22.6, exp fits fp32 easily)
#pragma unroll
    for (int u = 0; u < 2; u++) {
      unsigned short* lPu = lPw + u * 512;
#pragma unroll
      for (int r = 0; r < 4; r++) {
        int m = mrow + r;
        int sx = (m >> 1) & 3;
        float p0 = __expf(s0[u][r]);
        float p1 = __expf(s1[u][r]);
        lsum[u][r] += p0 + p1;
        int kc0 = l16 >> 3;
        lPu[m * 32 + ((kc0 ^ sx)) * 8 + (l16 & 7)] = f2bf(p0);        // keys 0..15
        lPu[m * 32 + (((kc0 + 2) ^ sx)) * 8 + (l16 & 7)] = f2bf(p1);  // keys 16..31
      }
    }
    // P: C-layout -> A-layout via LDS (in-wave ordered, no barrier needed)
    bf16x8 pf[2];
#pragma unroll
    for (int u = 0; u < 2; u++)
      pf[u] = *(const bf16x8*)(lPw + u * 512 + l16 * 32 + (quad ^ xsl) * 8);
    // O += P * V  (V frags read once, used by both subtiles)
#pragma unroll
    for (int t = 0; t < 8; t++) {
      bf16x8 vf = *(const bf16x8*)(lV + (t * 16 + l16) * 32 + (quad ^ xsl) * 8);
#pragma unroll
      for (int u = 0; u < 2; u++)
        o[u][t] = __builtin_amdgcn_mfma_f32_16x16x32_bf16(pf[u], vf, o[u][t], 0, 0, 0);
    }
  }

  // reduce row-sums across the 16 lanes of each quad
#pragma unroll
  for (int off = 1; off < 16; off <<= 1) {
#pragma unroll
    for (int u = 0; u < 2; u++)
#pragma unroll
      for (int r = 0; r < 4; r++) lsum[u][r] += __shfl_xor(lsum[u][r], off);
  }
  float inv[2][4];
#pragma unroll
  for (int u = 0; u < 2; u++)
#pragma unroll
    for (int r = 0; r < 4; r++) inv[u][r] = 1.0f / lsum[u][r];
#pragma unroll
  for (int u = 0; u < 2; u++)
#pragma unroll
    for (int t = 0; t < 8; t++)
#pragma unroll
      for (int r = 0; r < 4; r++) {
        size_t idx = ((size_t)b * S_ + q0 + u * 16 + mrow + r) * DM + h * HD + t * 16 + l16;
        Y[idx] = f2bf(o[u][t][r] * inv[u][r]);
      }
}

// ============================================================================
extern "C" void kernel_launch(void* const* d_in, const int* in_sizes, int n_in,
                              void* d_out, int out_size, void* d_ws, size_t ws_size,
                              hipStream_t stream) {
  const float* x    = (const float*)d_in[0];
  const float* ctx  = (const float*)d_in[1];
  const float* cosq = (const float*)d_in[2];
  const float* sinq = (const float*)d_in[3];
  const float* cosk = (const float*)d_in[4];
  const float* sink = (const float*)d_in[5];
  const float* Wq   = (const float*)d_in[6];
  const float* Wk   = (const float*)d_in[7];
  const float* Wv   = (const float*)d_in[8];
  const float* Wo   = (const float*)d_in[9];
  const float* qw   = (const float*)d_in[10];
  const float* kw   = (const float*)d_in[11];

  // ---- workspace layout with lifetime overlap (~101 MB) ----
  char* ws = (char*)d_ws;
  const size_t ACT2 = (size_t)M_ * DM * 2;   // 16.8 MB bf16 activation
  const size_t W2   = (size_t)DM * DM * 2;   // 8.4 MB bf16 weight
  unsigned short* xb  = (unsigned short*)(ws);                    // region0: xb -> qn
  unsigned short* cb  = (unsigned short*)(ws + ACT2);             // region1: cb -> vt
  unsigned short* Wqb = (unsigned short*)(ws + 2 * ACT2);         // region2: Wqb \ kn
  unsigned short* Wkb = (unsigned short*)(ws + 2 * ACT2 + W2);    // region3: Wkb /
  unsigned short* Wvb = (unsigned short*)(ws + 2 * ACT2 + 2 * W2);
  unsigned short* Wob = (unsigned short*)(ws + 2 * ACT2 + 3 * W2);
  float*          Pf  = (float*)(ws + 2 * ACT2 + 4 * W2);         // region6: Pf -> y
  unsigned short* qn = xb;          // after x consumed by gemm1
  unsigned short* kn = Wqb;         // spans Wqb+Wkb, both dead after gemm2
  unsigned short* vt = cb;          // after ctx consumed by gemm3
  unsigned short* yb = (unsigned short*)Pf;  // after Pf consumed by vtrans

  const float scale = 0.0883883476483184f;  // 1/sqrt(128)
  dim3 gg(M_ / 128, DM / 128);

  castbf<<<M_ * DM / 1024, 256, 0, stream>>>(x, xb, M_ * DM / 4);
  castbf<<<M_ * DM / 1024, 256, 0, stream>>>(ctx, cb, M_ * DM / 4);
  castbf<<<DM * DM / 1024, 256, 0, stream>>>(Wq, Wqb, DM * DM / 4);
  castbf<<<DM * DM / 1024, 256, 0, stream>>>(Wk, Wkb, DM * DM / 4);
  castbf<<<DM * DM / 1024, 256, 0, stream>>>(Wv, Wvb, DM * DM / 4);
  castbf<<<DM * DM / 1024, 256, 0, stream>>>(Wo, Wob, DM * DM / 4);

  gemm_bt<<<gg, 256, 0, stream>>>(xb, Wqb, Pf, M_, DM, DM);
  normrope<<<M_ * H_ / 4, 256, 0, stream>>>(Pf, cosq, sinq, qw, qn, scale);

  gemm_bt<<<gg, 256, 0, stream>>>(cb, Wkb, Pf, M_, DM, DM);
  normrope<<<M_ * H_ / 4, 256, 0, stream>>>(Pf, cosk, sink, kw, kn, 1.0f);

  gemm_bt<<<gg, 256, 0, stream>>>(cb, Wvb, Pf, M_, DM, DM);
  vtrans<<<B_ * H_ * (S_ / 64), 256, 0, stream>>>(Pf, vt);

  flash<<<B_ * H_ * (S_ / 128), 256, 0, stream>>>(qn, kn, vt, yb);

  gemm_bt<<<gg, 256, 0, stream>>>(yb, Wob, (float*)d_out, M_, DM, DM);

  (void)in_sizes; (void)n_in; (void)out_size; (void)ws_size;
}

// Round 3
// 496.077 us; speedup vs baseline: 1.1320x; 1.1320x over previous
//
#include <hip/hip_runtime.h>

// ============================================================================
// AdapterAttention on gfx950.
// R2: (a) QKV projections fused into ONE batched GEMM launch (grid.z=3,
//     1536 blocks = 6/CU vs 512 = 2/CU) with bf16 epilogue; (b) flash v3:
//     128-thread blocks, 64 q-rows/block (1024 blocks = 4 barrier domains/CU),
//     64-key chunks (32 iters, half the vmcnt-drain barriers). R1 lesson:
//     flash is latency/barrier-bound (Occ 20%, nothing saturated), not
//     LDS-throughput-bound.
// ============================================================================

typedef __attribute__((ext_vector_type(8))) short bf16x8;
typedef __attribute__((ext_vector_type(4))) float f32x4;

#define AS1(p) ((__attribute__((address_space(1))) void*)(p))
#define AS3(p) ((__attribute__((address_space(3))) void*)(p))

__device__ __forceinline__ unsigned short f2bf(float f) {
  unsigned int u = __float_as_uint(f);
  u += 0x7fffu + ((u >> 16) & 1u);   // RNE; inputs are finite
  return (unsigned short)(u >> 16);
}
__device__ __forceinline__ float bf2f(unsigned short u) {
  return __uint_as_float(((unsigned int)u) << 16);
}

constexpr int B_ = 2, S_ = 2048, DM = 2048, H_ = 16, HD = 128;
constexpr int M_ = B_ * S_;  // 4096 rows

// ---------------- fp32 -> bf16 cast (vec4) ----------------
__global__ __launch_bounds__(256) void castbf(const float* __restrict__ X,
                                              unsigned short* __restrict__ Y, int n4) {
  int i = blockIdx.x * 256 + threadIdx.x;
  if (i >= n4) return;
  float4 v = ((const float4*)X)[i];
  ushort4 u;
  u.x = f2bf(v.x); u.y = f2bf(v.y); u.z = f2bf(v.z); u.w = f2bf(v.w);
  ((ushort4*)Y)[i] = u;
}

// ---------------- batched QKV GEMM: P[z] = A[z] * W[z]^T, bf16 out ----------
// z=0: Q=x*Wq^T; z=1: K=ctx*Wk^T; z=2: V=ctx*Wv^T. 128x128 tile, BK=32.
__global__ __launch_bounds__(256) void gemm_qkv(const unsigned short* __restrict__ xb,
                                                const unsigned short* __restrict__ cb,
                                                const unsigned short* __restrict__ Wq,
                                                const unsigned short* __restrict__ Wk,
                                                const unsigned short* __restrict__ Wv,
                                                unsigned short* __restrict__ Pq,
                                                unsigned short* __restrict__ Pk,
                                                unsigned short* __restrict__ Pv) {
  __shared__ unsigned short lA[128 * 32];
  __shared__ unsigned short lB[128 * 32];
  const int z = blockIdx.z;
  const unsigned short* A  = (z == 0) ? xb : cb;
  const unsigned short* Bw = (z == 0) ? Wq : (z == 1) ? Wk : Wv;
  unsigned short* C        = (z == 0) ? Pq : (z == 1) ? Pk : Pv;
  const int tid = threadIdx.x, wave = tid >> 6, lane = tid & 63;
  const int quad = lane >> 4, l16 = lane & 15;
  const int m0 = blockIdx.x * 128, n0 = blockIdx.y * 128;
  const int wm = (wave >> 1) * 64, wn = (wave & 1) * 64;
  f32x4 acc[4][4];
#pragma unroll
  for (int i = 0; i < 4; i++)
#pragma unroll
    for (int j = 0; j < 4; j++) acc[i][j] = (f32x4){0.f, 0.f, 0.f, 0.f};

  for (int k0 = 0; k0 < DM; k0 += 32) {
    __syncthreads();
#pragma unroll
    for (int call = 0; call < 2; ++call) {
      int c = wave * 128 + call * 64 + lane;
      int row = c >> 2, s = c & 3;
      int dc = s ^ ((row >> 1) & 3);
      __builtin_amdgcn_global_load_lds(AS1(A + (size_t)(m0 + row) * DM + k0 + dc * 8),
                                       AS3(lA + (wave * 128 + call * 64) * 8), 16, 0, 0);
      __builtin_amdgcn_global_load_lds(AS1(Bw + (size_t)(n0 + row) * DM + k0 + dc * 8),
                                       AS3(lB + (wave * 128 + call * 64) * 8), 16, 0, 0);
    }
    __syncthreads();

    bf16x8 af[4], bfr[4];
#pragma unroll
    for (int i = 0; i < 4; i++) {
      int r = wm + i * 16 + l16;
      af[i] = *(const bf16x8*)(lA + r * 32 + (quad ^ ((r >> 1) & 3)) * 8);
      int cN = wn + i * 16 + l16;
      bfr[i] = *(const bf16x8*)(lB + cN * 32 + (quad ^ ((cN >> 1) & 3)) * 8);
    }
#pragma unroll
    for (int i = 0; i < 4; i++)
#pragma unroll
      for (int j = 0; j < 4; j++)
        acc[i][j] = __builtin_amdgcn_mfma_f32_16x16x32_bf16(af[i], bfr[j], acc[i][j], 0, 0, 0);
  }
#pragma unroll
  for (int i = 0; i < 4; i++)
#pragma unroll
    for (int j = 0; j < 4; j++) {
      unsigned short* cp = C + (size_t)(m0 + wm + i * 16 + quad * 4) * DM + (n0 + wn + j * 16 + l16);
#pragma unroll
      for (int r = 0; r < 4; r++) cp[(size_t)r * DM] = f2bf(acc[i][j][r]);
    }
}

// ---------------- bf16 GEMM: C = A * W^T (fp32 out), for out-proj -----------
__global__ __launch_bounds__(256) void gemm_bt(const unsigned short* __restrict__ A,
                                               const unsigned short* __restrict__ Bw,
                                               float* __restrict__ C,
                                               int M, int N, int K) {
  __shared__ unsigned short lA[128 * 32];
  __shared__ unsigned short lB[128 * 32];
  const int tid = threadIdx.x, wave = tid >> 6, lane = tid & 63;
  const int quad = lane >> 4, l16 = lane & 15;
  const int m0 = blockIdx.x * 128, n0 = blockIdx.y * 128;
  const int wm = (wave >> 1) * 64, wn = (wave & 1) * 64;
  f32x4 acc[4][4];
#pragma unroll
  for (int i = 0; i < 4; i++)
#pragma unroll
    for (int j = 0; j < 4; j++) acc[i][j] = (f32x4){0.f, 0.f, 0.f, 0.f};

  for (int k0 = 0; k0 < K; k0 += 32) {
    __syncthreads();
#pragma unroll
    for (int call = 0; call < 2; ++call) {
      int c = wave * 128 + call * 64 + lane;
      int row = c >> 2, s = c & 3;
      int dc = s ^ ((row >> 1) & 3);
      __builtin_amdgcn_global_load_lds(AS1(A + (size_t)(m0 + row) * K + k0 + dc * 8),
                                       AS3(lA + (wave * 128 + call * 64) * 8), 16, 0, 0);
      __builtin_amdgcn_global_load_lds(AS1(Bw + (size_t)(n0 + row) * K + k0 + dc * 8),
                                       AS3(lB + (wave * 128 + call * 64) * 8), 16, 0, 0);
    }
    __syncthreads();

    bf16x8 af[4], bfr[4];
#pragma unroll
    for (int i = 0; i < 4; i++) {
      int r = wm + i * 16 + l16;
      af[i] = *(const bf16x8*)(lA + r * 32 + (quad ^ ((r >> 1) & 3)) * 8);
      int cN = wn + i * 16 + l16;
      bfr[i] = *(const bf16x8*)(lB + cN * 32 + (quad ^ ((cN >> 1) & 3)) * 8);
    }
#pragma unroll
    for (int i = 0; i < 4; i++)
#pragma unroll
      for (int j = 0; j < 4; j++)
        acc[i][j] = __builtin_amdgcn_mfma_f32_16x16x32_bf16(af[i], bfr[j], acc[i][j], 0, 0, 0);
  }
#pragma unroll
  for (int i = 0; i < 4; i++)
#pragma unroll
    for (int j = 0; j < 4; j++) {
      float* cp = C + (size_t)(m0 + wm + i * 16 + quad * 4) * N + (n0 + wn + j * 16 + l16);
#pragma unroll
      for (int r = 0; r < 4; r++) cp[(size_t)r * N] = acc[i][j][r];
    }
}

// ---------------- fused RMSNorm + RoPE, bf16 (B,S,H,hd) -> (B,H,S,hd) bf16 --
__global__ __launch_bounds__(256) void normrope(const unsigned short* __restrict__ X,
                                                const float* __restrict__ Cs,
                                                const float* __restrict__ Sn,
                                                const float* __restrict__ W,
                                                unsigned short* __restrict__ Out,
                                                float scale) {
  int gw = (blockIdx.x * 256 + threadIdx.x) >> 6;  // (b*S+s)*H + h
  int lane = threadIdx.x & 63;
  int h = gw & 15, bs = gw >> 4;          // bs = b*S + s
  int s = bs & (S_ - 1), b = bs >> 11;
  const unsigned short* xr = X + (size_t)gw * HD;
  float x0 = bf2f(xr[lane]), x1 = bf2f(xr[lane + 64]);
  float ss = x0 * x0 + x1 * x1;
#pragma unroll
  for (int off = 32; off > 0; off >>= 1) ss += __shfl_xor(ss, off);
  float rr = rsqrtf(ss * (1.0f / 128.0f) + 1e-6f);
  float n0 = x0 * rr * W[lane], n1 = x1 * rr * W[lane + 64];
  const float* cp = Cs + (size_t)bs * HD;
  const float* sp = Sn + (size_t)bs * HD;
  float o0 = (n0 * cp[lane] - n1 * sp[lane]) * scale;
  float o1 = (n1 * cp[lane + 64] + n0 * sp[lane + 64]) * scale;
  unsigned short* orow = Out + (((size_t)(b * H_ + h)) * S_ + s) * HD;
  orow[lane] = f2bf(o0);
  orow[lane + 64] = f2bf(o1);
}

// ---------------- V: bf16 (B,S,H,hd) -> (B*H, hd, Sk) bf16 (transposed) -----
__global__ __launch_bounds__(256) void vtrans(const unsigned short* __restrict__ Vf,
                                              unsigned short* __restrict__ Vt) {
  __shared__ unsigned short tile[128 * 72];  // [d][s], stride 72
  const int tid = threadIdx.x;
  const int sc = blockIdx.x & 31;
  const int bh = blockIdx.x >> 5;
  const int b = bh >> 4, h = bh & 15;
  const int s0 = sc * 64;
#pragma unroll
  for (int it = 0; it < 4; ++it) {
    int ci = it * 256 + tid;                  // 1024 chunks: 64 s x 16 dc
    int s = ci >> 4, dc = ci & 15;
    bf16x8 v = *(const bf16x8*)(Vf + ((size_t)(b * S_ + s0 + s)) * DM + h * HD + dc * 8);
    unsigned short* tp = tile + (dc * 8) * 72 + s;
#pragma unroll
    for (int e = 0; e < 8; e++) tp[e * 72] = (unsigned short)v[e];
  }
  __syncthreads();
#pragma unroll
  for (int it = 0; it < 4; ++it) {
    int cj = it * 256 + tid;                  // 1024 16B chunks: 128 d x 8 sc
    int d = cj >> 3, scx = cj & 7;
    bf16x8 vv = *(const bf16x8*)(tile + d * 72 + scx * 8);
    *(bf16x8*)(Vt + ((size_t)bh * HD + d) * S_ + s0 + scx * 8) = vv;
  }
}

// ---------------- flash attention v3 ----------------
// 128 threads (2 waves), 64 q-rows/block (32/wave), 64-key chunks.
// Q (BH,Sq,128) bf16 scale-baked; K (BH,Sk,128); V (BH,128,Sk); Y (B,Sq,2048) bf16
__global__ __launch_bounds__(128) void flash(const unsigned short* __restrict__ Q,
                                             const unsigned short* __restrict__ Kt,
                                             const unsigned short* __restrict__ Vt,
                                             unsigned short* __restrict__ Y) {
  __shared__ unsigned short lK[64 * HD];      // [key][dim], chunk-swizzled
  __shared__ unsigned short lV[HD * 64];      // [dim][key], chunk-swizzled
  __shared__ unsigned short lP[2 * 1024];     // per-wave P scratch (reused per half)
  const int tid = threadIdx.x, wave = tid >> 6, lane = tid & 63;
  const int quad = lane >> 4, l16 = lane & 15;
  const int qb = blockIdx.x & 31;   // Sq/64
  const int bh = blockIdx.x >> 5;
  const int b = bh >> 4, h = bh & 15;
  const int q0 = qb * 64 + wave * 32;

  bf16x8 aq[2][4];
#pragma unroll
  for (int u = 0; u < 2; u++) {
    const unsigned short* qrow = Q + ((size_t)bh * S_ + q0 + u * 16 + l16) * HD;
#pragma unroll
    for (int t = 0; t < 4; t++) aq[u][t] = *(const bf16x8*)(qrow + t * 32 + quad * 8);
  }
  f32x4 o[2][8];
#pragma unroll
  for (int u = 0; u < 2; u++)
#pragma unroll
    for (int t = 0; t < 8; t++) o[u][t] = (f32x4){0.f, 0.f, 0.f, 0.f};
  float lsum[2][4] = {{0.f, 0.f, 0.f, 0.f}, {0.f, 0.f, 0.f, 0.f}};

  const unsigned short* kbase = Kt + (size_t)bh * S_ * HD;
  const unsigned short* vbase = Vt + (size_t)bh * HD * S_;
  unsigned short* lPw = lP + wave * 1024;
  const int mrow = quad * 4;
  const int xsl = (l16 >> 1) & 3;    // P-read swizzle (4 chunks per 32-key row)
  const int xsl7 = (l16 >> 1) & 7;   // V-read swizzle (8 chunks per 64-key row)

  for (int k0 = 0; k0 < S_; k0 += 64) {
    __syncthreads();
#pragma unroll
    for (int call = 0; call < 8; ++call) {
      int c = call * 128 + wave * 64 + lane;  // 1024 chunks of 16B each
      int key = c >> 4, sk = c & 15;          // K: 64 keys x 16 dim-chunks
      int dck = sk ^ (key & 15);
      __builtin_amdgcn_global_load_lds(AS1(kbase + (size_t)(k0 + key) * HD + dck * 8),
                                       AS3(lK + (call * 128 + wave * 64) * 8), 16, 0, 0);
      int dv = c >> 3, sv = c & 7;            // V: 128 dims x 8 key-chunks
      int kc = sv ^ ((dv >> 1) & 7);
      __builtin_amdgcn_global_load_lds(AS1(vbase + (size_t)dv * S_ + k0 + kc * 8),
                                       AS3(lV + (call * 128 + wave * 64) * 8), 16, 0, 0);
    }
    __syncthreads();

#pragma unroll
    for (int h2 = 0; h2 < 2; ++h2) {          // two 32-key halves
      // S = Q*K^T  (two 16-key tiles x two 16-row q subtiles; K frags shared)
      f32x4 s0[2] = {(f32x4){0.f, 0.f, 0.f, 0.f}, (f32x4){0.f, 0.f, 0.f, 0.f}};
      f32x4 s1[2] = {(f32x4){0.f, 0.f, 0.f, 0.f}, (f32x4){0.f, 0.f, 0.f, 0.f}};
      {
        const unsigned short* krow0 = lK + (h2 * 32 + l16) * HD;
        const unsigned short* krow1 = krow0 + 16 * HD;
#pragma unroll
        for (int t = 0; t < 4; t++) {
          int dcq = t * 4 + quad;
          bf16x8 kf0 = *(const bf16x8*)(krow0 + (dcq ^ l16) * 8);
          bf16x8 kf1 = *(const bf16x8*)(krow1 + (dcq ^ l16) * 8);
#pragma unroll
          for (int u = 0; u < 2; u++) {
            s0[u] = __builtin_amdgcn_mfma_f32_16x16x32_bf16(aq[u][t], kf0, s0[u], 0, 0, 0);
            s1[u] = __builtin_amdgcn_mfma_f32_16x16x32_bf16(aq[u][t], kf1, s1[u], 0, 0, 0);
          }
        }
      }
      // softmax numerator (no max subtraction: |s| <= 22.6)
#pragma unroll
      for (int u = 0; u < 2; u++) {
        unsigned short* lPu = lPw + u * 512;
#pragma unroll
        for (int r = 0; r < 4; r++) {
          int m = mrow + r;
          int sx = (m >> 1) & 3;
          float p0 = __expf(s0[u][r]);
          float p1 = __expf(s1[u][r]);
          lsum[u][r] += p0 + p1;
          int kc0 = l16 >> 3;
          lPu[m * 32 + ((kc0 ^ sx)) * 8 + (l16 & 7)] = f2bf(p0);
          lPu[m * 32 + (((kc0 + 2) ^ sx)) * 8 + (l16 & 7)] = f2bf(p1);
        }
      }
      // P: C-layout -> A-layout via LDS (in-wave ordered, no barrier needed)
      bf16x8 pf[2];
#pragma unroll
      for (int u = 0; u < 2; u++)
        pf[u] = *(const bf16x8*)(lPw + u * 512 + l16 * 32 + (quad ^ xsl) * 8);
      // O += P * V  (V frags shared across u)
#pragma unroll
      for (int t = 0; t < 8; t++) {
        bf16x8 vf = *(const bf16x8*)(lV + (t * 16 + l16) * 64 + ((h2 * 4 + quad) ^ xsl7) * 8);
#pragma unroll
        for (int u = 0; u < 2; u++)
          o[u][t] = __builtin_amdgcn_mfma_f32_16x16x32_bf16(pf[u], vf, o[u][t], 0, 0, 0);
      }
    }
  }

  // reduce row-sums across the 16 lanes of each quad
#pragma unroll
  for (int off = 1; off < 16; off <<= 1) {
#pragma unroll
    for (int u = 0; u < 2; u++)
#pragma unroll
      for (int r = 0; r < 4; r++) lsum[u][r] += __shfl_xor(lsum[u][r], off);
  }
  float inv[2][4];
#pragma unroll
  for (int u = 0; u < 2; u++)
#pragma unroll
    for (int r = 0; r < 4; r++) inv[u][r] = 1.0f / lsum[u][r];
#pragma unroll
  for (int u = 0; u < 2; u++)
#pragma unroll
    for (int t = 0; t < 8; t++)
#pragma unroll
      for (int r = 0; r < 4; r++) {
        size_t idx = ((size_t)b * S_ + q0 + u * 16 + mrow + r) * DM + h * HD + t * 16 + l16;
        Y[idx] = f2bf(o[u][t][r] * inv[u][r]);
      }
}

// ============================================================================
extern "C" void kernel_launch(void* const* d_in, const int* in_sizes, int n_in,
                              void* d_out, int out_size, void* d_ws, size_t ws_size,
                              hipStream_t stream) {
  const float* x    = (const float*)d_in[0];
  const float* ctx  = (const float*)d_in[1];
  const float* cosq = (const float*)d_in[2];
  const float* sinq = (const float*)d_in[3];
  const float* cosk = (const float*)d_in[4];
  const float* sink = (const float*)d_in[5];
  const float* Wq   = (const float*)d_in[6];
  const float* Wk   = (const float*)d_in[7];
  const float* Wv   = (const float*)d_in[8];
  const float* Wo   = (const float*)d_in[9];
  const float* qw   = (const float*)d_in[10];
  const float* kw   = (const float*)d_in[11];

  // ---- workspace layout with lifetime overlap (~118 MB) ----
  char* ws = (char*)d_ws;
  const size_t ACT2 = (size_t)M_ * DM * 2;   // 16.8 MB bf16 activation
  const size_t W2   = (size_t)DM * DM * 2;   // 8.4 MB bf16 weight
  unsigned short* xb  = (unsigned short*)(ws);                    // -> qn
  unsigned short* cb  = (unsigned short*)(ws + ACT2);             // -> vt
  unsigned short* Wqb = (unsigned short*)(ws + 2 * ACT2);         // \ kn
  unsigned short* Wkb = (unsigned short*)(ws + 2 * ACT2 + W2);    // /
  unsigned short* Wvb = (unsigned short*)(ws + 2 * ACT2 + 2 * W2);
  unsigned short* Wob = (unsigned short*)(ws + 2 * ACT2 + 3 * W2);
  unsigned short* Pq  = (unsigned short*)(ws + 2 * ACT2 + 4 * W2);  // -> yb
  unsigned short* Pk  = (unsigned short*)(ws + 3 * ACT2 + 4 * W2);
  unsigned short* Pv  = (unsigned short*)(ws + 4 * ACT2 + 4 * W2);
  unsigned short* qn = xb;          // after gemm_qkv consumed xb
  unsigned short* kn = Wqb;         // spans Wqb+Wkb, dead after gemm_qkv
  unsigned short* vt = cb;          // after gemm_qkv consumed cb
  unsigned short* yb = Pq;          // after normrope consumed Pq

  const float scale = 0.0883883476483184f;  // 1/sqrt(128)

  castbf<<<M_ * DM / 1024, 256, 0, stream>>>(x, xb, M_ * DM / 4);
  castbf<<<M_ * DM / 1024, 256, 0, stream>>>(ctx, cb, M_ * DM / 4);
  castbf<<<DM * DM / 1024, 256, 0, stream>>>(Wq, Wqb, DM * DM / 4);
  castbf<<<DM * DM / 1024, 256, 0, stream>>>(Wk, Wkb, DM * DM / 4);
  castbf<<<DM * DM / 1024, 256, 0, stream>>>(Wv, Wvb, DM * DM / 4);
  castbf<<<DM * DM / 1024, 256, 0, stream>>>(Wo, Wob, DM * DM / 4);

  dim3 gq(M_ / 128, DM / 128, 3);   // 32 x 16 x 3 = 1536 blocks
  gemm_qkv<<<gq, 256, 0, stream>>>(xb, cb, Wqb, Wkb, Wvb, Pq, Pk, Pv);

  normrope<<<M_ * H_ / 4, 256, 0, stream>>>(Pq, cosq, sinq, qw, qn, scale);
  normrope<<<M_ * H_ / 4, 256, 0, stream>>>(Pk, cosk, sink, kw, kn, 1.0f);
  vtrans<<<B_ * H_ * (S_ / 64), 256, 0, stream>>>(Pv, vt);

  flash<<<B_ * H_ * (S_ / 64), 128, 0, stream>>>(qn, kn, vt, yb);

  dim3 gg(M_ / 128, DM / 128);
  gemm_bt<<<gg, 256, 0, stream>>>(yb, Wob, (float*)d_out, M_, DM, DM);

  (void)in_sizes; (void)n_in; (void)out_size; (void)ws_size;
}